// Round 7
// baseline (568.937 us; speedup 1.0000x reference)
//
#include <hip/hip_runtime.h>
#include <hip/hip_fp16.h>

#define NFEAT 128
#define EPSV 1e-5f
#define BSH 9
#define BSZ 512   // nodes per dst-bucket

typedef _Float16 h8 __attribute__((ext_vector_type(8)));   // 8 halfs = 16B
typedef float f4 __attribute__((ext_vector_type(4)));

// ---------------- column stats (mean/var over N rows, 128 cols) ----------------
__global__ __launch_bounds__(256) void k_stats(const float* __restrict__ X,
    float* __restrict__ sum, float* __restrict__ sumsq, long total)
{
    float s = 0.f, q = 0.f;
    long stride = (long)gridDim.x * blockDim.x;
    for (long i = (long)blockIdx.x * blockDim.x + threadIdx.x; i < total; i += stride) {
        float v = X[i];
        s += v;
        q = fmaf(v, v, q);
    }
    __shared__ float ls[256], lq[256];
    ls[threadIdx.x] = s; lq[threadIdx.x] = q;
    __syncthreads();
    if (threadIdx.x < 128) {
        int c = threadIdx.x;            // stride is a multiple of 128 -> col == tid&127
        s = ls[c] + ls[c + 128];
        q = lq[c] + lq[c + 128];
        unsafeAtomicAdd(&sum[c], s);
        unsafeAtomicAdd(&sumsq[c], q);
    }
}

// ---------------- BN apply: xn = (x-mu)*rstd*gamma + beta  (write f16) ----------
__global__ __launch_bounds__(256) void k_bn(const float* __restrict__ X,
    const float* __restrict__ sum, const float* __restrict__ sumsq,
    const float* __restrict__ gamma, const float* __restrict__ beta,
    __half* __restrict__ XN, long total4, float invN)
{
    __shared__ float sc[NFEAT], sh[NFEAT];
    if (threadIdx.x < NFEAT) {
        int c = threadIdx.x;
        float mu = sum[c] * invN;
        float var = fmaf(-mu, mu, sumsq[c] * invN);
        float r = rsqrtf(var + EPSV);
        float g = r * gamma[c];
        sc[c] = g;
        sh[c] = fmaf(-mu, g, beta[c]);
    }
    __syncthreads();
    const float4* X4 = (const float4*)X;
    uint2* XN4 = (uint2*)XN;
    long stride = (long)gridDim.x * blockDim.x;
    for (long i = (long)blockIdx.x * blockDim.x + threadIdx.x; i < total4; i += stride) {
        int c0 = (int)((i << 2) & (NFEAT - 1));
        float4 v = X4[i];
        float4 o;
        o.x = fmaf(v.x, sc[c0 + 0], sh[c0 + 0]);
        o.y = fmaf(v.y, sc[c0 + 1], sh[c0 + 1]);
        o.z = fmaf(v.z, sc[c0 + 2], sh[c0 + 2]);
        o.w = fmaf(v.w, sc[c0 + 3], sh[c0 + 3]);
        __half2 h0 = __floats2half2_rn(o.x, o.y);
        __half2 h1 = __floats2half2_rn(o.z, o.w);
        uint2 u;
        u.x = *(unsigned int*)&h0;
        u.y = *(unsigned int*)&h1;
        XN4[i] = u;
    }
}

// ---------------- bucket histogram over dst>>BSH ----------------
__global__ __launch_bounds__(256) void k_bhist(const int* __restrict__ dst,
    int* __restrict__ bcnt, int E, int NB)
{
    __shared__ int hist[1024];
    for (int i = threadIdx.x; i < NB; i += 256) hist[i] = 0;
    __syncthreads();
    int stride = gridDim.x * 256;
    for (int e = blockIdx.x * 256 + threadIdx.x; e < E; e += stride)
        atomicAdd(&hist[dst[e] >> BSH], 1);
    __syncthreads();
    for (int i = threadIdx.x; i < NB; i += 256)
        if (hist[i]) atomicAdd(&bcnt[i], hist[i]);
}

// ---------------- scan bucket counts (NB <= 256) -> boff[NB+1], bnxt ----------------
__global__ __launch_bounds__(256) void k_bscan(const int* __restrict__ bcnt,
    int* __restrict__ boff, int* __restrict__ bnxt, int NB)
{
    __shared__ int ps[256];
    int t = threadIdx.x;
    int v = (t < NB) ? bcnt[t] : 0;
    ps[t] = v;
    __syncthreads();
    #pragma unroll
    for (int off = 1; off < 256; off <<= 1) {
        int u = ps[t];
        if (t >= off) u += ps[t - off];
        __syncthreads();
        ps[t] = u;
        __syncthreads();
    }
    if (t < NB) {
        int ex = ps[t] - v;
        boff[t] = ex;
        bnxt[t] = ex;
    }
    if (t == NB - 1) boff[NB] = ps[t];
}

// ---------------- partition edges into buckets, packed (src<<BSH | dst&511) ----------
__global__ __launch_bounds__(256) void k_bucket(const int* __restrict__ src,
    const int* __restrict__ dst, int* __restrict__ bnxt,
    int* __restrict__ packed, int E, int NB)
{
    __shared__ int hist[1024];
    __shared__ int base[1024];
    int c0 = blockIdx.x * 8192;
    int c1 = min(E, c0 + 8192);
    for (int i = threadIdx.x; i < NB; i += 256) hist[i] = 0;
    __syncthreads();
    for (int e = c0 + threadIdx.x; e < c1; e += 256)
        atomicAdd(&hist[dst[e] >> BSH], 1);
    __syncthreads();
    for (int i = threadIdx.x; i < NB; i += 256) {
        int h = hist[i];
        base[i] = h ? atomicAdd(&bnxt[i], h) : 0;
        hist[i] = 0;
    }
    __syncthreads();
    for (int e = c0 + threadIdx.x; e < c1; e += 256) {
        int d = dst[e];
        int b = d >> BSH;
        int p = base[b] + atomicAdd(&hist[b], 1);
        packed[p] = (src[e] << BSH) | (d & (BSZ - 1));
    }
}

// ---------------- per-bucket degree (LDS counters -> coalesced deg writes) --------
__global__ __launch_bounds__(256) void k_bdeg(const int* __restrict__ packed,
    const int* __restrict__ boff, int* __restrict__ deg, int N)
{
    __shared__ int cnt[BSZ];
    int b = blockIdx.x;
    for (int i = threadIdx.x; i < BSZ; i += 256) cnt[i] = 0;
    __syncthreads();
    int e0 = boff[b], e1 = boff[b + 1];
    for (int e = e0 + threadIdx.x; e < e1; e += 256)
        atomicAdd(&cnt[packed[e] & (BSZ - 1)], 1);
    __syncthreads();
    int nbase = b << BSH;
    for (int i = threadIdx.x; i < BSZ; i += 256)
        if (nbase + i < N) deg[nbase + i] = cnt[i];
}

// ---------------- 3-phase device-wide exclusive scan ----------------
__global__ __launch_bounds__(256) void k_scan_a(const int* __restrict__ deg,
    int* __restrict__ part, int N)
{
    int base = blockIdx.x << 10;
    int t = threadIdx.x;
    int s = 0;
    #pragma unroll
    for (int j = 0; j < 4; ++j) {
        int i = base + t * 4 + j;
        if (i < N) s += deg[i];
    }
    __shared__ int ls[256];
    ls[t] = s;
    __syncthreads();
    #pragma unroll
    for (int off = 128; off > 0; off >>= 1) {
        if (t < off) ls[t] += ls[t + off];
        __syncthreads();
    }
    if (t == 0) part[blockIdx.x] = ls[0];
}

__global__ __launch_bounds__(256) void k_scan_b(int* __restrict__ part, int nb)
{
    __shared__ int ps[256];
    int t = threadIdx.x;
    int v = (t < nb) ? part[t] : 0;
    ps[t] = v;
    __syncthreads();
    #pragma unroll
    for (int off = 1; off < 256; off <<= 1) {
        int u = ps[t];
        if (t >= off) u += ps[t - off];
        __syncthreads();
        ps[t] = u;
        __syncthreads();
    }
    if (t < nb) part[t] = ps[t] - v;   // exclusive
}

__global__ __launch_bounds__(256) void k_scan_c(const int* __restrict__ deg,
    const int* __restrict__ part, int* __restrict__ rp,
    float* __restrict__ dinv, int N, int E)
{
    int base = blockIdx.x << 10;
    int t = threadIdx.x;
    int v[4];
    int ts = 0;
    #pragma unroll
    for (int j = 0; j < 4; ++j) {
        int i = base + t * 4 + j;
        v[j] = (i < N) ? deg[i] : 0;
        ts += v[j];
    }
    __shared__ int ps[256];
    ps[t] = ts;
    __syncthreads();
    #pragma unroll
    for (int off = 1; off < 256; off <<= 1) {
        int u = ps[t];
        if (t >= off) u += ps[t - off];
        __syncthreads();
        ps[t] = u;
        __syncthreads();
    }
    int run = part[blockIdx.x] + ps[t] - ts;   // exclusive offset for this thread
    #pragma unroll
    for (int j = 0; j < 4; ++j) {
        int i = base + t * 4 + j;
        if (i < N) {
            rp[i] = run;
            dinv[i] = rsqrtf((float)(v[j] + 1));
            run += v[j];
        }
    }
    if (blockIdx.x == 0 && t == 0) rp[N] = E;
}

// ---------------- per-bucket CSR placement (writes confined to 33KB window) ------
__global__ __launch_bounds__(256) void k_place(const int* __restrict__ packed,
    const int* __restrict__ boff, const int* __restrict__ rp,
    int* __restrict__ csr, int N)
{
    __shared__ int nxt[BSZ];
    int b = blockIdx.x;
    int nbase = b << BSH;
    for (int i = threadIdx.x; i < BSZ; i += 256)
        nxt[i] = (nbase + i < N) ? rp[nbase + i] : 0;
    __syncthreads();
    int e0 = boff[b], e1 = boff[b + 1];
    for (int e = e0 + threadIdx.x; e < e1; e += 256) {
        int v = packed[e];
        int p = atomicAdd(&nxt[v & (BSZ - 1)], 1);
        csr[p] = v >> BSH;
    }
}

// ---------------- MFMA GEMM: Ys[s][n][16] = dinv[n] * (X[n]@W^T)[s*16..]  --------
// One wave per 16-row tile. W staged once/block to LDS f16 (stride 136 halfs ->
// bank-conflict-free b128 reads). A-frag: lane l = row(l&15), kgroup(l>>4), 16B
// contiguous global load. D-frag (measured): col=lane&15, row=(lane>>4)*4+reg.
// Output written in SLICED layout: slice s = n-tile, [s][node][16] f16 (3.2MB/slice).
__global__ __launch_bounds__(256) void k_gemm_mfma(const _Float16* __restrict__ X,
    const float* __restrict__ W, const float* __restrict__ dinv,
    _Float16* __restrict__ Ys, int N)
{
    __shared__ _Float16 w16[NFEAT * 136];   // [o][k], row stride 136
    for (int idx = threadIdx.x; idx < NFEAT * NFEAT; idx += 256) {
        int o = idx >> 7, k = idx & 127;
        w16[o * 136 + k] = (_Float16)W[idx];
    }
    __syncthreads();

    const h8* Xv = (const h8*)X;            // 16 h8-chunks per row
    const h8* Wv = (const h8*)w16;          // 17 h8-chunks per row
    int lane = threadIdx.x & 63;
    int lr = lane & 15;                      // row-in-tile / out-col
    int lk = lane >> 4;                      // k-subgroup (0..3)
    int wid = (blockIdx.x * blockDim.x + threadIdx.x) >> 6;
    int nw = (gridDim.x * blockDim.x) >> 6;
    int ntiles = N >> 4;

    for (int tile = wid; tile < ntiles; tile += nw) {
        int r0 = tile << 4;
        h8 a[4];
        #pragma unroll
        for (int kg = 0; kg < 4; ++kg)
            a[kg] = Xv[(long)(r0 + lr) * 16 + kg * 4 + lk];

        f4 acc[8];
        #pragma unroll
        for (int nt = 0; nt < 8; ++nt) acc[nt] = (f4)(0.f);

        #pragma unroll
        for (int nt = 0; nt < 8; ++nt) {
            int o = nt * 16 + lr;
            #pragma unroll
            for (int kg = 0; kg < 4; ++kg) {
                h8 b = Wv[o * 17 + kg * 4 + lk];
                acc[nt] = __builtin_amdgcn_mfma_f32_16x16x32_f16(a[kg], b, acc[nt], 0, 0, 0);
            }
        }

        int rbase = r0 + (lane >> 4) * 4;
        float dv0 = dinv[rbase + 0];
        float dv1 = dinv[rbase + 1];
        float dv2 = dinv[rbase + 2];
        float dv3 = dinv[rbase + 3];
        #pragma unroll
        for (int nt = 0; nt < 8; ++nt) {
            _Float16* dst = Ys + ((long)nt * N) * 16 + lr;
            dst[(long)(rbase + 0) * 16] = (_Float16)(acc[nt][0] * dv0);
            dst[(long)(rbase + 1) * 16] = (_Float16)(acc[nt][1] * dv1);
            dst[(long)(rbase + 2) * 16] = (_Float16)(acc[nt][2] * dv2);
            dst[(long)(rbase + 3) * 16] = (_Float16)(acc[nt][3] * dv3);
        }
    }
}

// ---------------- sliced aggregation, full-wave: one wave per (node, slice) -------
// 64 lanes = 16 edge-slots x 4 feature-subwords (uint2 = 8B -> 32B/edge row).
// slice = blockIdx&7 (XCD-pinned, 3.2MB table L2-resident). Avg degree 16 ->
// most waves do ONE gather iteration; tail lanes clamp to a cached row, x0.
__global__ __launch_bounds__(256) void k_agg(const uint2* __restrict__ TTs,
    const int* __restrict__ rp, const int* __restrict__ csr,
    const float* __restrict__ dinv, const float* __restrict__ bias,
    uint2* __restrict__ OUT, int N)
{
    int s = blockIdx.x & 7;
    int ng0 = blockIdx.x >> 3;
    int ngStride = gridDim.x >> 3;
    int lane = threadIdx.x & 63;
    int sub = lane & 3;          // 8B sub-chunk of the 32B slice row
    int slot = lane >> 2;        // edge slot 0..15
    const uint2* base = TTs + (long)s * N * 4;   // slice table: N rows x 4 uint2

    for (int ng = ng0; ng * 4 < N; ng += ngStride) {
        int node = ng * 4 + (threadIdx.x >> 6);
        if (node >= N) continue;
        int e0 = rp[node], e1 = rp[node + 1];
        float4 acc = make_float4(0.f, 0.f, 0.f, 0.f);
        for (int e = e0; e < e1; e += 16) {
            int idx = e + slot;
            bool valid = idx < e1;
            int src = csr[valid ? idx : (e1 - 1)];
            uint2 v = base[(long)src * 4 + sub];
            float2 fa = __half22float2(*(const __half2*)&v.x);
            float2 fb = __half22float2(*(const __half2*)&v.y);
            float m = valid ? 1.f : 0.f;
            acc.x = fmaf(fa.x, m, acc.x);
            acc.y = fmaf(fa.y, m, acc.y);
            acc.z = fmaf(fb.x, m, acc.z);
            acc.w = fmaf(fb.y, m, acc.w);
        }
        #pragma unroll
        for (int off = 4; off < 64; off <<= 1) {
            acc.x += __shfl_xor(acc.x, off);
            acc.y += __shfl_xor(acc.y, off);
            acc.z += __shfl_xor(acc.z, off);
            acc.w += __shfl_xor(acc.w, off);
        }
        if (slot == 0) {   // lanes 0..3 finalize 16 features
            uint2 sv = base[(long)node * 4 + sub];
            float2 sa = __half22float2(*(const __half2*)&sv.x);
            float2 sb = __half22float2(*(const __half2*)&sv.y);
            float dv = dinv[node];
            int fb0 = s * 16 + sub * 4;
            float o0 = fmaxf(fmaf(acc.x + sa.x, dv, bias[fb0 + 0]), 0.f);
            float o1 = fmaxf(fmaf(acc.y + sa.y, dv, bias[fb0 + 1]), 0.f);
            float o2 = fmaxf(fmaf(acc.z + sb.x, dv, bias[fb0 + 2]), 0.f);
            float o3 = fmaxf(fmaf(acc.w + sb.y, dv, bias[fb0 + 3]), 0.f);
            __half2 p0 = __floats2half2_rn(o0, o1);
            __half2 p1 = __floats2half2_rn(o2, o3);
            uint2 u;
            u.x = *(unsigned int*)&p0;
            u.y = *(unsigned int*)&p1;
            // node row = 128 f16 = 32 uint2 (round-6 bug was stride 16)
            OUT[(long)node * 32 + s * 4 + sub] = u;   // row-major f16 [node][128]
        }
    }
}

// ---------------- fused head: relu(H@Wc1^T + bc1) @ Wc2^T + bc2  (H f16) ---------
__global__ __launch_bounds__(256) void k_head(const __half* __restrict__ H,
    const float* __restrict__ Wc1, const float* __restrict__ bc1,
    const float* __restrict__ Wc2, const float* __restrict__ bc2,
    float* __restrict__ OUT, int N)
{
    __shared__ float w1[16][132];
    __shared__ float hs[16][132];
    __shared__ float h16[16][17];
    for (int idx = threadIdx.x; idx < 16 * NFEAT; idx += 256) {
        int o = idx >> 7, k = idx & 127;
        w1[o][k] = Wc1[idx];
    }
    const unsigned int* Hu = (const unsigned int*)H;
    int ntiles = (N + 15) >> 4;
    for (int tile = blockIdx.x; tile < ntiles; tile += gridDim.x) {
        int row0 = tile << 4;
        __syncthreads();   // also covers w1 init on first iter
        #pragma unroll
        for (int it = 0; it < 4; ++it) {
            int idx = it * 256 + threadIdx.x;   // 0..1023
            int r = idx >> 6, p = idx & 63;
            int row = row0 + r;
            unsigned int v = (row < N) ? Hu[(long)row * 64 + p] : 0u;
            float2 f = __half22float2(*(const __half2*)&v);
            hs[r][p * 2] = f.x;
            hs[r][p * 2 + 1] = f.y;
        }
        __syncthreads();
        int r = threadIdx.x >> 4, o = threadIdx.x & 15;
        float acc = 0.f;
        #pragma unroll 8
        for (int k = 0; k < NFEAT; ++k) acc = fmaf(hs[r][k], w1[o][k], acc);
        h16[r][o] = fmaxf(acc + bc1[o], 0.f);
        __syncthreads();
        if (threadIdx.x < 32) {
            int rr = threadIdx.x >> 1, j = threadIdx.x & 1;
            float a = bc2[j];
            #pragma unroll
            for (int o2 = 0; o2 < 16; ++o2) a = fmaf(h16[rr][o2], Wc2[j * 16 + o2], a);
            int row = row0 + rr;
            if (row < N) OUT[(long)row * 2 + j] = a;
        }
        __syncthreads();
    }
}

extern "C" void kernel_launch(void* const* d_in, const int* in_sizes, int n_in,
                              void* d_out, int out_size, void* d_ws, size_t ws_size,
                              hipStream_t stream) {
    const float* x     = (const float*)d_in[0];
    const int*   ei    = (const int*)d_in[1];
    const float* gamma = (const float*)d_in[2];
    const float* beta  = (const float*)d_in[3];
    const float* W1    = (const float*)d_in[4];
    const float* b1    = (const float*)d_in[5];
    const float* W2    = (const float*)d_in[6];
    const float* b2    = (const float*)d_in[7];
    const float* Wc1   = (const float*)d_in[8];
    const float* bc1   = (const float*)d_in[9];
    const float* Wc2   = (const float*)d_in[10];
    const float* bc2   = (const float*)d_in[11];

    int N = in_sizes[0] / NFEAT;
    int E = in_sizes[1] / 2;
    const int* srcI = ei;
    const int* dstI = ei + E;
    int NB = (N + BSZ - 1) >> BSH;   // 196 for N=100k (<=256 required by k_bscan)

    char* ws = (char*)d_ws;
    size_t off = 0;
    auto alloc = [&](size_t bytes) {
        void* p = ws + off;
        off += bytes;
        off = (off + 511) & ~(size_t)511;
        return p;
    };
    __half* bufA  = (__half*)alloc((size_t)N * NFEAT * 2);   // h buffer (row-major)
    __half* bufB  = (__half*)alloc((size_t)N * NFEAT * 2);   // tt buffer (sliced)
    float* sum    = (float*)alloc(NFEAT * 4);
    float* sumsq  = (float*)alloc(NFEAT * 4);
    int*   deg    = (int*)alloc((size_t)N * 4);
    int*   rp     = (int*)alloc((size_t)(N + 1) * 4);
    float* dinv   = (float*)alloc((size_t)N * 4);
    int*   csr    = (int*)alloc((size_t)E * 4);
    int*   packed = (int*)alloc((size_t)E * 4);
    int*   bcnt   = (int*)alloc((size_t)(NB + 1) * 4);
    int*   boff   = (int*)alloc((size_t)(NB + 1) * 4);
    int*   bnxt   = (int*)alloc((size_t)(NB + 1) * 4);
    int*   part   = (int*)alloc(256 * 4);
    (void)ws_size;

    hipMemsetAsync(sum, 0, NFEAT * 4, stream);
    hipMemsetAsync(sumsq, 0, NFEAT * 4, stream);
    hipMemsetAsync(bcnt, 0, (size_t)(NB + 1) * 4, stream);

    long total = (long)N * NFEAT;
    int nb = (N + 1023) >> 10;          // scan blocks
    int nchunk = (E + 8191) >> 13;      // bucket partition blocks (8192 edges each)
    int naggb = 16384;                  // agg: 2048 node-group blocks x 8 slices

    k_stats<<<1024, 256, 0, stream>>>(x, sum, sumsq, total);
    k_bn<<<2048, 256, 0, stream>>>(x, sum, sumsq, gamma, beta, bufA, total >> 2, 1.0f / (float)N);

    // graph build (bucketed counting sort, L2-window scatter)
    k_bhist<<<NB, 256, 0, stream>>>(dstI, bcnt, E, NB);
    k_bscan<<<1, 256, 0, stream>>>(bcnt, boff, bnxt, NB);
    k_bucket<<<nchunk, 256, 0, stream>>>(srcI, dstI, bnxt, packed, E, NB);
    k_bdeg<<<NB, 256, 0, stream>>>(packed, boff, deg, N);
    k_scan_a<<<nb, 256, 0, stream>>>(deg, part, N);
    k_scan_b<<<1, 256, 0, stream>>>(part, nb);
    k_scan_c<<<nb, 256, 0, stream>>>(deg, part, rp, dinv, N, E);
    k_place<<<NB, 256, 0, stream>>>(packed, boff, rp, csr, N);

    // layer 1
    k_gemm_mfma<<<512, 256, 0, stream>>>((const _Float16*)bufA, W1, dinv, (_Float16*)bufB, N);
    k_agg<<<naggb, 256, 0, stream>>>((const uint2*)bufB, rp, csr, dinv, b1, (uint2*)bufA, N);
    // layer 2
    k_gemm_mfma<<<512, 256, 0, stream>>>((const _Float16*)bufA, W2, dinv, (_Float16*)bufB, N);
    k_agg<<<naggb, 256, 0, stream>>>((const uint2*)bufB, rp, csr, dinv, b2, (uint2*)bufA, N);
    // head
    k_head<<<2048, 256, 0, stream>>>(bufA, Wc1, bc1, Wc2, bc2, (float*)d_out, N);
}

// Round 8
// 368.799 us; speedup vs baseline: 1.5427x; 1.5427x over previous
//
#include <hip/hip_runtime.h>
#include <hip/hip_fp16.h>

#define NFEAT 128
#define EPSV 1e-5f
#define BSH 9
#define BSZ 512   // nodes per dst-bucket

typedef _Float16 h8 __attribute__((ext_vector_type(8)));   // 8 halfs = 16B
typedef float f4 __attribute__((ext_vector_type(4)));

// ---------------- column stats (mean/var over N rows, 128 cols) ----------------
__global__ __launch_bounds__(256) void k_stats(const float* __restrict__ X,
    float* __restrict__ sum, float* __restrict__ sumsq, long total)
{
    float s = 0.f, q = 0.f;
    long stride = (long)gridDim.x * blockDim.x;
    for (long i = (long)blockIdx.x * blockDim.x + threadIdx.x; i < total; i += stride) {
        float v = X[i];
        s += v;
        q = fmaf(v, v, q);
    }
    __shared__ float ls[256], lq[256];
    ls[threadIdx.x] = s; lq[threadIdx.x] = q;
    __syncthreads();
    if (threadIdx.x < 128) {
        int c = threadIdx.x;            // stride is a multiple of 128 -> col == tid&127
        s = ls[c] + ls[c + 128];
        q = lq[c] + lq[c + 128];
        unsafeAtomicAdd(&sum[c], s);
        unsafeAtomicAdd(&sumsq[c], q);
    }
}

// ---------------- BN apply: xn = (x-mu)*rstd*gamma + beta  (write f16) ----------
__global__ __launch_bounds__(256) void k_bn(const float* __restrict__ X,
    const float* __restrict__ sum, const float* __restrict__ sumsq,
    const float* __restrict__ gamma, const float* __restrict__ beta,
    __half* __restrict__ XN, long total4, float invN)
{
    __shared__ float sc[NFEAT], sh[NFEAT];
    if (threadIdx.x < NFEAT) {
        int c = threadIdx.x;
        float mu = sum[c] * invN;
        float var = fmaf(-mu, mu, sumsq[c] * invN);
        float r = rsqrtf(var + EPSV);
        float g = r * gamma[c];
        sc[c] = g;
        sh[c] = fmaf(-mu, g, beta[c]);
    }
    __syncthreads();
    const float4* X4 = (const float4*)X;
    uint2* XN4 = (uint2*)XN;
    long stride = (long)gridDim.x * blockDim.x;
    for (long i = (long)blockIdx.x * blockDim.x + threadIdx.x; i < total4; i += stride) {
        int c0 = (int)((i << 2) & (NFEAT - 1));
        float4 v = X4[i];
        float4 o;
        o.x = fmaf(v.x, sc[c0 + 0], sh[c0 + 0]);
        o.y = fmaf(v.y, sc[c0 + 1], sh[c0 + 1]);
        o.z = fmaf(v.z, sc[c0 + 2], sh[c0 + 2]);
        o.w = fmaf(v.w, sc[c0 + 3], sh[c0 + 3]);
        __half2 h0 = __floats2half2_rn(o.x, o.y);
        __half2 h1 = __floats2half2_rn(o.z, o.w);
        uint2 u;
        u.x = *(unsigned int*)&h0;
        u.y = *(unsigned int*)&h1;
        XN4[i] = u;
    }
}

// ---------------- bucket histogram over dst>>BSH ----------------
__global__ __launch_bounds__(256) void k_bhist(const int* __restrict__ dst,
    int* __restrict__ bcnt, int E, int NB)
{
    __shared__ int hist[1024];
    for (int i = threadIdx.x; i < NB; i += 256) hist[i] = 0;
    __syncthreads();
    int stride = gridDim.x * 256;
    for (int e = blockIdx.x * 256 + threadIdx.x; e < E; e += stride)
        atomicAdd(&hist[dst[e] >> BSH], 1);
    __syncthreads();
    for (int i = threadIdx.x; i < NB; i += 256)
        if (hist[i]) atomicAdd(&bcnt[i], hist[i]);
}

// ---------------- scan bucket counts (NB <= 256) -> boff[NB+1], bnxt ----------------
__global__ __launch_bounds__(256) void k_bscan(const int* __restrict__ bcnt,
    int* __restrict__ boff, int* __restrict__ bnxt, int NB)
{
    __shared__ int ps[256];
    int t = threadIdx.x;
    int v = (t < NB) ? bcnt[t] : 0;
    ps[t] = v;
    __syncthreads();
    #pragma unroll
    for (int off = 1; off < 256; off <<= 1) {
        int u = ps[t];
        if (t >= off) u += ps[t - off];
        __syncthreads();
        ps[t] = u;
        __syncthreads();
    }
    if (t < NB) {
        int ex = ps[t] - v;
        boff[t] = ex;
        bnxt[t] = ex;
    }
    if (t == NB - 1) boff[NB] = ps[t];
}

// ---------------- partition edges into buckets, packed (src<<BSH | dst&511) ----------
__global__ __launch_bounds__(256) void k_bucket(const int* __restrict__ src,
    const int* __restrict__ dst, int* __restrict__ bnxt,
    int* __restrict__ packed, int E, int NB)
{
    __shared__ int hist[1024];
    __shared__ int base[1024];
    int c0 = blockIdx.x * 8192;
    int c1 = min(E, c0 + 8192);
    for (int i = threadIdx.x; i < NB; i += 256) hist[i] = 0;
    __syncthreads();
    for (int e = c0 + threadIdx.x; e < c1; e += 256)
        atomicAdd(&hist[dst[e] >> BSH], 1);
    __syncthreads();
    for (int i = threadIdx.x; i < NB; i += 256) {
        int h = hist[i];
        base[i] = h ? atomicAdd(&bnxt[i], h) : 0;
        hist[i] = 0;
    }
    __syncthreads();
    for (int e = c0 + threadIdx.x; e < c1; e += 256) {
        int d = dst[e];
        int b = d >> BSH;
        int p = base[b] + atomicAdd(&hist[b], 1);
        packed[p] = (src[e] << BSH) | (d & (BSZ - 1));
    }
}

// ---------------- per-bucket degree (LDS counters -> coalesced deg writes) --------
__global__ __launch_bounds__(256) void k_bdeg(const int* __restrict__ packed,
    const int* __restrict__ boff, int* __restrict__ deg, int N)
{
    __shared__ int cnt[BSZ];
    int b = blockIdx.x;
    for (int i = threadIdx.x; i < BSZ; i += 256) cnt[i] = 0;
    __syncthreads();
    int e0 = boff[b], e1 = boff[b + 1];
    for (int e = e0 + threadIdx.x; e < e1; e += 256)
        atomicAdd(&cnt[packed[e] & (BSZ - 1)], 1);
    __syncthreads();
    int nbase = b << BSH;
    for (int i = threadIdx.x; i < BSZ; i += 256)
        if (nbase + i < N) deg[nbase + i] = cnt[i];
}

// ---------------- 3-phase device-wide exclusive scan ----------------
__global__ __launch_bounds__(256) void k_scan_a(const int* __restrict__ deg,
    int* __restrict__ part, int N)
{
    int base = blockIdx.x << 10;
    int t = threadIdx.x;
    int s = 0;
    #pragma unroll
    for (int j = 0; j < 4; ++j) {
        int i = base + t * 4 + j;
        if (i < N) s += deg[i];
    }
    __shared__ int ls[256];
    ls[t] = s;
    __syncthreads();
    #pragma unroll
    for (int off = 128; off > 0; off >>= 1) {
        if (t < off) ls[t] += ls[t + off];
        __syncthreads();
    }
    if (t == 0) part[blockIdx.x] = ls[0];
}

__global__ __launch_bounds__(256) void k_scan_b(int* __restrict__ part, int nb)
{
    __shared__ int ps[256];
    int t = threadIdx.x;
    int v = (t < nb) ? part[t] : 0;
    ps[t] = v;
    __syncthreads();
    #pragma unroll
    for (int off = 1; off < 256; off <<= 1) {
        int u = ps[t];
        if (t >= off) u += ps[t - off];
        __syncthreads();
        ps[t] = u;
        __syncthreads();
    }
    if (t < nb) part[t] = ps[t] - v;   // exclusive
}

__global__ __launch_bounds__(256) void k_scan_c(const int* __restrict__ deg,
    const int* __restrict__ part, int* __restrict__ rp,
    float* __restrict__ dinv, int N, int E)
{
    int base = blockIdx.x << 10;
    int t = threadIdx.x;
    int v[4];
    int ts = 0;
    #pragma unroll
    for (int j = 0; j < 4; ++j) {
        int i = base + t * 4 + j;
        v[j] = (i < N) ? deg[i] : 0;
        ts += v[j];
    }
    __shared__ int ps[256];
    ps[t] = ts;
    __syncthreads();
    #pragma unroll
    for (int off = 1; off < 256; off <<= 1) {
        int u = ps[t];
        if (t >= off) u += ps[t - off];
        __syncthreads();
        ps[t] = u;
        __syncthreads();
    }
    int run = part[blockIdx.x] + ps[t] - ts;   // exclusive offset for this thread
    #pragma unroll
    for (int j = 0; j < 4; ++j) {
        int i = base + t * 4 + j;
        if (i < N) {
            rp[i] = run;
            dinv[i] = rsqrtf((float)(v[j] + 1));
            run += v[j];
        }
    }
    if (blockIdx.x == 0 && t == 0) rp[N] = E;
}

// ---------------- per-bucket CSR placement (writes confined to 33KB window) ------
__global__ __launch_bounds__(256) void k_place(const int* __restrict__ packed,
    const int* __restrict__ boff, const int* __restrict__ rp,
    int* __restrict__ csr, int N)
{
    __shared__ int nxt[BSZ];
    int b = blockIdx.x;
    int nbase = b << BSH;
    for (int i = threadIdx.x; i < BSZ; i += 256)
        nxt[i] = (nbase + i < N) ? rp[nbase + i] : 0;
    __syncthreads();
    int e0 = boff[b], e1 = boff[b + 1];
    for (int e = e0 + threadIdx.x; e < e1; e += 256) {
        int v = packed[e];
        int p = atomicAdd(&nxt[v & (BSZ - 1)], 1);
        csr[p] = v >> BSH;
    }
}

// ---------------- MFMA GEMM: Ys[s][n][16] = dinv[n] * (X[n]@W^T)[s*16..]  --------
// One wave per 16-row tile. W staged once/block to LDS f16 (stride 136 halfs ->
// bank-conflict-free b128 reads). A-frag: lane l = row(l&15), kgroup(l>>4), 16B
// contiguous global load. D-frag (measured): col=lane&15, row=(lane>>4)*4+reg.
// Output written in SLICED layout: slice s = n-tile, [s][node][16] f16 (3.2MB/slice).
__global__ __launch_bounds__(256) void k_gemm_mfma(const _Float16* __restrict__ X,
    const float* __restrict__ W, const float* __restrict__ dinv,
    _Float16* __restrict__ Ys, int N)
{
    __shared__ _Float16 w16[NFEAT * 136];   // [o][k], row stride 136
    for (int idx = threadIdx.x; idx < NFEAT * NFEAT; idx += 256) {
        int o = idx >> 7, k = idx & 127;
        w16[o * 136 + k] = (_Float16)W[idx];
    }
    __syncthreads();

    const h8* Xv = (const h8*)X;            // 16 h8-chunks per row
    const h8* Wv = (const h8*)w16;          // 17 h8-chunks per row
    int lane = threadIdx.x & 63;
    int lr = lane & 15;                      // row-in-tile / out-col
    int lk = lane >> 4;                      // k-subgroup (0..3)
    int wid = (blockIdx.x * blockDim.x + threadIdx.x) >> 6;
    int nw = (gridDim.x * blockDim.x) >> 6;
    int ntiles = N >> 4;

    for (int tile = wid; tile < ntiles; tile += nw) {
        int r0 = tile << 4;
        h8 a[4];
        #pragma unroll
        for (int kg = 0; kg < 4; ++kg)
            a[kg] = Xv[(long)(r0 + lr) * 16 + kg * 4 + lk];

        f4 acc[8];
        #pragma unroll
        for (int nt = 0; nt < 8; ++nt) acc[nt] = (f4)(0.f);

        #pragma unroll
        for (int nt = 0; nt < 8; ++nt) {
            int o = nt * 16 + lr;
            #pragma unroll
            for (int kg = 0; kg < 4; ++kg) {
                h8 b = Wv[o * 17 + kg * 4 + lk];
                acc[nt] = __builtin_amdgcn_mfma_f32_16x16x32_f16(a[kg], b, acc[nt], 0, 0, 0);
            }
        }

        int rbase = r0 + (lane >> 4) * 4;
        float dv0 = dinv[rbase + 0];
        float dv1 = dinv[rbase + 1];
        float dv2 = dinv[rbase + 2];
        float dv3 = dinv[rbase + 3];
        #pragma unroll
        for (int nt = 0; nt < 8; ++nt) {
            _Float16* dst = Ys + ((long)nt * N) * 16 + lr;
            dst[(long)(rbase + 0) * 16] = (_Float16)(acc[nt][0] * dv0);
            dst[(long)(rbase + 1) * 16] = (_Float16)(acc[nt][1] * dv1);
            dst[(long)(rbase + 2) * 16] = (_Float16)(acc[nt][2] * dv2);
            dst[(long)(rbase + 3) * 16] = (_Float16)(acc[nt][3] * dv3);
        }
    }
}

// ---------------- sliced aggregation, in-lane accumulate, zero shuffles ----------
// block = (node-group of 32, slice = blockIdx&7, XCD-pinned; 3.2MB table -> L2).
// wave = 8 groups x 8 lanes; group owns ONE node; lane holds half2 (4B) of the
// node's 32B slice row. Per group-iteration: gather 1 edge row (wave instr = 8
// edges x 32B), accumulate in-lane. Lane-varying edge loop -> exec-mask handles
// degree imbalance; 4-edge unroll (clamp+mask) for memory-level parallelism.
__global__ __launch_bounds__(256) void k_agg(const unsigned int* __restrict__ TTs,
    const int* __restrict__ rp, const int* __restrict__ csr,
    const float* __restrict__ dinv, const float* __restrict__ bias,
    unsigned int* __restrict__ OUT, int N)
{
    int s = blockIdx.x & 7;
    int g = blockIdx.x >> 3;
    int t = threadIdx.x;
    int node = g * 32 + (t >> 3);
    if (node >= N) return;
    int ln = t & 7;                               // lane within group (feature sub)
    const unsigned int* base = TTs + (long)s * N * 8;   // slice: N rows x 8 uints

    int e0 = rp[node], e1 = rp[node + 1];
    float accx = 0.f, accy = 0.f;
    for (int e = e0; e < e1; e += 4) {
        #pragma unroll
        for (int j = 0; j < 4; ++j) {
            int k = e + j;
            bool valid = k < e1;
            int src = csr[valid ? k : e0];
            unsigned int v = base[(long)src * 8 + ln];
            float2 f = __half22float2(*(const __half2*)&v);
            float m = valid ? 1.f : 0.f;
            accx = fmaf(f.x, m, accx);
            accy = fmaf(f.y, m, accy);
        }
    }
    unsigned int sv = base[(long)node * 8 + ln];   // self-loop term
    float2 sf = __half22float2(*(const __half2*)&sv);
    float dv = dinv[node];
    int fb = s * 16 + ln * 2;
    float ox = fmaxf(fmaf(accx + sf.x, dv, bias[fb + 0]), 0.f);
    float oy = fmaxf(fmaf(accy + sf.y, dv, bias[fb + 1]), 0.f);
    __half2 o2 = __floats2half2_rn(ox, oy);
    // node row = 128 f16 = 64 uints
    OUT[(long)node * 64 + s * 8 + ln] = *(unsigned int*)&o2;
}

// ---------------- fused head: relu(H@Wc1^T + bc1) @ Wc2^T + bc2  (H f16) ---------
__global__ __launch_bounds__(256) void k_head(const __half* __restrict__ H,
    const float* __restrict__ Wc1, const float* __restrict__ bc1,
    const float* __restrict__ Wc2, const float* __restrict__ bc2,
    float* __restrict__ OUT, int N)
{
    __shared__ float w1[16][132];
    __shared__ float hs[16][132];
    __shared__ float h16[16][17];
    for (int idx = threadIdx.x; idx < 16 * NFEAT; idx += 256) {
        int o = idx >> 7, k = idx & 127;
        w1[o][k] = Wc1[idx];
    }
    const unsigned int* Hu = (const unsigned int*)H;
    int ntiles = (N + 15) >> 4;
    for (int tile = blockIdx.x; tile < ntiles; tile += gridDim.x) {
        int row0 = tile << 4;
        __syncthreads();   // also covers w1 init on first iter
        #pragma unroll
        for (int it = 0; it < 4; ++it) {
            int idx = it * 256 + threadIdx.x;   // 0..1023
            int r = idx >> 6, p = idx & 63;
            int row = row0 + r;
            unsigned int v = (row < N) ? Hu[(long)row * 64 + p] : 0u;
            float2 f = __half22float2(*(const __half2*)&v);
            hs[r][p * 2] = f.x;
            hs[r][p * 2 + 1] = f.y;
        }
        __syncthreads();
        int r = threadIdx.x >> 4, o = threadIdx.x & 15;
        float acc = 0.f;
        #pragma unroll 8
        for (int k = 0; k < NFEAT; ++k) acc = fmaf(hs[r][k], w1[o][k], acc);
        h16[r][o] = fmaxf(acc + bc1[o], 0.f);
        __syncthreads();
        if (threadIdx.x < 32) {
            int rr = threadIdx.x >> 1, j = threadIdx.x & 1;
            float a = bc2[j];
            #pragma unroll
            for (int o2 = 0; o2 < 16; ++o2) a = fmaf(h16[rr][o2], Wc2[j * 16 + o2], a);
            int row = row0 + rr;
            if (row < N) OUT[(long)row * 2 + j] = a;
        }
        __syncthreads();
    }
}

extern "C" void kernel_launch(void* const* d_in, const int* in_sizes, int n_in,
                              void* d_out, int out_size, void* d_ws, size_t ws_size,
                              hipStream_t stream) {
    const float* x     = (const float*)d_in[0];
    const int*   ei    = (const int*)d_in[1];
    const float* gamma = (const float*)d_in[2];
    const float* beta  = (const float*)d_in[3];
    const float* W1    = (const float*)d_in[4];
    const float* b1    = (const float*)d_in[5];
    const float* W2    = (const float*)d_in[6];
    const float* b2    = (const float*)d_in[7];
    const float* Wc1   = (const float*)d_in[8];
    const float* bc1   = (const float*)d_in[9];
    const float* Wc2   = (const float*)d_in[10];
    const float* bc2   = (const float*)d_in[11];

    int N = in_sizes[0] / NFEAT;
    int E = in_sizes[1] / 2;
    const int* srcI = ei;
    const int* dstI = ei + E;
    int NB = (N + BSZ - 1) >> BSH;   // 196 for N=100k (<=256 required by k_bscan)

    char* ws = (char*)d_ws;
    size_t off = 0;
    auto alloc = [&](size_t bytes) {
        void* p = ws + off;
        off += bytes;
        off = (off + 511) & ~(size_t)511;
        return p;
    };
    __half* bufA  = (__half*)alloc((size_t)N * NFEAT * 2);   // h buffer (row-major)
    __half* bufB  = (__half*)alloc((size_t)N * NFEAT * 2);   // tt buffer (sliced)
    float* sum    = (float*)alloc(NFEAT * 4);
    float* sumsq  = (float*)alloc(NFEAT * 4);
    int*   deg    = (int*)alloc((size_t)N * 4);
    int*   rp     = (int*)alloc((size_t)(N + 1) * 4);
    float* dinv   = (float*)alloc((size_t)N * 4);
    int*   csr    = (int*)alloc((size_t)E * 4);
    int*   packed = (int*)alloc((size_t)E * 4);
    int*   bcnt   = (int*)alloc((size_t)(NB + 1) * 4);
    int*   boff   = (int*)alloc((size_t)(NB + 1) * 4);
    int*   bnxt   = (int*)alloc((size_t)(NB + 1) * 4);
    int*   part   = (int*)alloc(256 * 4);
    (void)ws_size;

    hipMemsetAsync(sum, 0, NFEAT * 4, stream);
    hipMemsetAsync(sumsq, 0, NFEAT * 4, stream);
    hipMemsetAsync(bcnt, 0, (size_t)(NB + 1) * 4, stream);

    long total = (long)N * NFEAT;
    int nb = (N + 1023) >> 10;          // scan blocks
    int nchunk = (E + 8191) >> 13;      // bucket partition blocks (8192 edges each)
    int naggb = ((N + 31) / 32) * 8;    // agg: node-groups (32 nodes/block) x 8 slices

    k_stats<<<1024, 256, 0, stream>>>(x, sum, sumsq, total);
    k_bn<<<2048, 256, 0, stream>>>(x, sum, sumsq, gamma, beta, bufA, total >> 2, 1.0f / (float)N);

    // graph build (bucketed counting sort, L2-window scatter)
    k_bhist<<<NB, 256, 0, stream>>>(dstI, bcnt, E, NB);
    k_bscan<<<1, 256, 0, stream>>>(bcnt, boff, bnxt, NB);
    k_bucket<<<nchunk, 256, 0, stream>>>(srcI, dstI, bnxt, packed, E, NB);
    k_bdeg<<<NB, 256, 0, stream>>>(packed, boff, deg, N);
    k_scan_a<<<nb, 256, 0, stream>>>(deg, part, N);
    k_scan_b<<<1, 256, 0, stream>>>(part, nb);
    k_scan_c<<<nb, 256, 0, stream>>>(deg, part, rp, dinv, N, E);
    k_place<<<NB, 256, 0, stream>>>(packed, boff, rp, csr, N);

    // layer 1
    k_gemm_mfma<<<512, 256, 0, stream>>>((const _Float16*)bufA, W1, dinv, (_Float16*)bufB, N);
    k_agg<<<naggb, 256, 0, stream>>>((const unsigned int*)bufB, rp, csr, dinv, b1, (unsigned int*)bufA, N);
    // layer 2
    k_gemm_mfma<<<512, 256, 0, stream>>>((const _Float16*)bufA, W2, dinv, (_Float16*)bufB, N);
    k_agg<<<naggb, 256, 0, stream>>>((const unsigned int*)bufB, rp, csr, dinv, b2, (unsigned int*)bufA, N);
    // head
    k_head<<<2048, 256, 0, stream>>>(bufA, Wc1, bc1, Wc2, bc2, (float*)d_out, N);
}

// Round 9
// 367.046 us; speedup vs baseline: 1.5500x; 1.0048x over previous
//
#include <hip/hip_runtime.h>
#include <hip/hip_fp16.h>

#define NFEAT 128
#define EPSV 1e-5f
#define BSH 9
#define BSZ 512   // nodes per dst-bucket

typedef _Float16 h8 __attribute__((ext_vector_type(8)));   // 8 halfs = 16B
typedef float f4 __attribute__((ext_vector_type(4)));

// ---------------- column stats (mean/var over N rows, 128 cols) ----------------
__global__ __launch_bounds__(256) void k_stats(const float* __restrict__ X,
    float* __restrict__ sum, float* __restrict__ sumsq, long total)
{
    float s = 0.f, q = 0.f;
    long stride = (long)gridDim.x * blockDim.x;
    for (long i = (long)blockIdx.x * blockDim.x + threadIdx.x; i < total; i += stride) {
        float v = X[i];
        s += v;
        q = fmaf(v, v, q);
    }
    __shared__ float ls[256], lq[256];
    ls[threadIdx.x] = s; lq[threadIdx.x] = q;
    __syncthreads();
    if (threadIdx.x < 128) {
        int c = threadIdx.x;            // stride is a multiple of 128 -> col == tid&127
        s = ls[c] + ls[c + 128];
        q = lq[c] + lq[c + 128];
        unsafeAtomicAdd(&sum[c], s);
        unsafeAtomicAdd(&sumsq[c], q);
    }
}

// ---------------- BN apply: xn = (x-mu)*rstd*gamma + beta  (write f16) ----------
__global__ __launch_bounds__(256) void k_bn(const float* __restrict__ X,
    const float* __restrict__ sum, const float* __restrict__ sumsq,
    const float* __restrict__ gamma, const float* __restrict__ beta,
    __half* __restrict__ XN, long total4, float invN)
{
    __shared__ float sc[NFEAT], sh[NFEAT];
    if (threadIdx.x < NFEAT) {
        int c = threadIdx.x;
        float mu = sum[c] * invN;
        float var = fmaf(-mu, mu, sumsq[c] * invN);
        float r = rsqrtf(var + EPSV);
        float g = r * gamma[c];
        sc[c] = g;
        sh[c] = fmaf(-mu, g, beta[c]);
    }
    __syncthreads();
    const float4* X4 = (const float4*)X;
    uint2* XN4 = (uint2*)XN;
    long stride = (long)gridDim.x * blockDim.x;
    for (long i = (long)blockIdx.x * blockDim.x + threadIdx.x; i < total4; i += stride) {
        int c0 = (int)((i << 2) & (NFEAT - 1));
        float4 v = X4[i];
        float4 o;
        o.x = fmaf(v.x, sc[c0 + 0], sh[c0 + 0]);
        o.y = fmaf(v.y, sc[c0 + 1], sh[c0 + 1]);
        o.z = fmaf(v.z, sc[c0 + 2], sh[c0 + 2]);
        o.w = fmaf(v.w, sc[c0 + 3], sh[c0 + 3]);
        __half2 h0 = __floats2half2_rn(o.x, o.y);
        __half2 h1 = __floats2half2_rn(o.z, o.w);
        uint2 u;
        u.x = *(unsigned int*)&h0;
        u.y = *(unsigned int*)&h1;
        XN4[i] = u;
    }
}

// ---------------- bucket histogram over dst>>BSH ----------------
__global__ __launch_bounds__(256) void k_bhist(const int* __restrict__ dst,
    int* __restrict__ bcnt, int E, int NB)
{
    __shared__ int hist[1024];
    for (int i = threadIdx.x; i < NB; i += 256) hist[i] = 0;
    __syncthreads();
    int stride = gridDim.x * 256;
    for (int e = blockIdx.x * 256 + threadIdx.x; e < E; e += stride)
        atomicAdd(&hist[dst[e] >> BSH], 1);
    __syncthreads();
    for (int i = threadIdx.x; i < NB; i += 256)
        if (hist[i]) atomicAdd(&bcnt[i], hist[i]);
}

// ---------------- scan bucket counts (NB <= 256) -> boff[NB+1], bnxt ----------------
__global__ __launch_bounds__(256) void k_bscan(const int* __restrict__ bcnt,
    int* __restrict__ boff, int* __restrict__ bnxt, int NB)
{
    __shared__ int ps[256];
    int t = threadIdx.x;
    int v = (t < NB) ? bcnt[t] : 0;
    ps[t] = v;
    __syncthreads();
    #pragma unroll
    for (int off = 1; off < 256; off <<= 1) {
        int u = ps[t];
        if (t >= off) u += ps[t - off];
        __syncthreads();
        ps[t] = u;
        __syncthreads();
    }
    if (t < NB) {
        int ex = ps[t] - v;
        boff[t] = ex;
        bnxt[t] = ex;
    }
    if (t == NB - 1) boff[NB] = ps[t];
}

// ---------------- partition edges into buckets, packed (src<<BSH | dst&511) ----------
__global__ __launch_bounds__(256) void k_bucket(const int* __restrict__ src,
    const int* __restrict__ dst, int* __restrict__ bnxt,
    int* __restrict__ packed, int E, int NB)
{
    __shared__ int hist[1024];
    __shared__ int base[1024];
    int c0 = blockIdx.x * 8192;
    int c1 = min(E, c0 + 8192);
    for (int i = threadIdx.x; i < NB; i += 256) hist[i] = 0;
    __syncthreads();
    for (int e = c0 + threadIdx.x; e < c1; e += 256)
        atomicAdd(&hist[dst[e] >> BSH], 1);
    __syncthreads();
    for (int i = threadIdx.x; i < NB; i += 256) {
        int h = hist[i];
        base[i] = h ? atomicAdd(&bnxt[i], h) : 0;
        hist[i] = 0;
    }
    __syncthreads();
    for (int e = c0 + threadIdx.x; e < c1; e += 256) {
        int d = dst[e];
        int b = d >> BSH;
        int p = base[b] + atomicAdd(&hist[b], 1);
        packed[p] = (src[e] << BSH) | (d & (BSZ - 1));
    }
}

// ---------------- per-bucket degree (LDS counters -> coalesced deg writes) --------
__global__ __launch_bounds__(256) void k_bdeg(const int* __restrict__ packed,
    const int* __restrict__ boff, int* __restrict__ deg, int N)
{
    __shared__ int cnt[BSZ];
    int b = blockIdx.x;
    for (int i = threadIdx.x; i < BSZ; i += 256) cnt[i] = 0;
    __syncthreads();
    int e0 = boff[b], e1 = boff[b + 1];
    for (int e = e0 + threadIdx.x; e < e1; e += 256)
        atomicAdd(&cnt[packed[e] & (BSZ - 1)], 1);
    __syncthreads();
    int nbase = b << BSH;
    for (int i = threadIdx.x; i < BSZ; i += 256)
        if (nbase + i < N) deg[nbase + i] = cnt[i];
}

// ---------------- 3-phase device-wide exclusive scan ----------------
__global__ __launch_bounds__(256) void k_scan_a(const int* __restrict__ deg,
    int* __restrict__ part, int N)
{
    int base = blockIdx.x << 10;
    int t = threadIdx.x;
    int s = 0;
    #pragma unroll
    for (int j = 0; j < 4; ++j) {
        int i = base + t * 4 + j;
        if (i < N) s += deg[i];
    }
    __shared__ int ls[256];
    ls[t] = s;
    __syncthreads();
    #pragma unroll
    for (int off = 128; off > 0; off >>= 1) {
        if (t < off) ls[t] += ls[t + off];
        __syncthreads();
    }
    if (t == 0) part[blockIdx.x] = ls[0];
}

__global__ __launch_bounds__(256) void k_scan_b(int* __restrict__ part, int nb)
{
    __shared__ int ps[256];
    int t = threadIdx.x;
    int v = (t < nb) ? part[t] : 0;
    ps[t] = v;
    __syncthreads();
    #pragma unroll
    for (int off = 1; off < 256; off <<= 1) {
        int u = ps[t];
        if (t >= off) u += ps[t - off];
        __syncthreads();
        ps[t] = u;
        __syncthreads();
    }
    if (t < nb) part[t] = ps[t] - v;   // exclusive
}

__global__ __launch_bounds__(256) void k_scan_c(const int* __restrict__ deg,
    const int* __restrict__ part, int* __restrict__ rp,
    float* __restrict__ dinv, int N, int E)
{
    int base = blockIdx.x << 10;
    int t = threadIdx.x;
    int v[4];
    int ts = 0;
    #pragma unroll
    for (int j = 0; j < 4; ++j) {
        int i = base + t * 4 + j;
        v[j] = (i < N) ? deg[i] : 0;
        ts += v[j];
    }
    __shared__ int ps[256];
    ps[t] = ts;
    __syncthreads();
    #pragma unroll
    for (int off = 1; off < 256; off <<= 1) {
        int u = ps[t];
        if (t >= off) u += ps[t - off];
        __syncthreads();
        ps[t] = u;
        __syncthreads();
    }
    int run = part[blockIdx.x] + ps[t] - ts;   // exclusive offset for this thread
    #pragma unroll
    for (int j = 0; j < 4; ++j) {
        int i = base + t * 4 + j;
        if (i < N) {
            rp[i] = run;
            dinv[i] = rsqrtf((float)(v[j] + 1));
            run += v[j];
        }
    }
    if (blockIdx.x == 0 && t == 0) rp[N] = E;
}

// ---------------- per-bucket CSR placement (writes confined to 33KB window) ------
__global__ __launch_bounds__(256) void k_place(const int* __restrict__ packed,
    const int* __restrict__ boff, const int* __restrict__ rp,
    int* __restrict__ csr, int N)
{
    __shared__ int nxt[BSZ];
    int b = blockIdx.x;
    int nbase = b << BSH;
    for (int i = threadIdx.x; i < BSZ; i += 256)
        nxt[i] = (nbase + i < N) ? rp[nbase + i] : 0;
    __syncthreads();
    int e0 = boff[b], e1 = boff[b + 1];
    for (int e = e0 + threadIdx.x; e < e1; e += 256) {
        int v = packed[e];
        int p = atomicAdd(&nxt[v & (BSZ - 1)], 1);
        csr[p] = v >> BSH;
    }
}

// ---------------- MFMA GEMM: Ys[s][n][16] = dinv[n] * (X[n]@W^T)[s*16..]  --------
// One wave per 16-row tile. W staged once/block to LDS f16 (stride 136 halfs ->
// bank-conflict-free b128 reads). A-frag: lane l = row(l&15), kgroup(l>>4), 16B
// contiguous global load. D-frag (measured): col=lane&15, row=(lane>>4)*4+reg.
// Output written in SLICED layout: slice s = n-tile, [s][node][16] f16 (3.2MB/slice).
__global__ __launch_bounds__(256) void k_gemm_mfma(const _Float16* __restrict__ X,
    const float* __restrict__ W, const float* __restrict__ dinv,
    _Float16* __restrict__ Ys, int N)
{
    __shared__ _Float16 w16[NFEAT * 136];   // [o][k], row stride 136
    for (int idx = threadIdx.x; idx < NFEAT * NFEAT; idx += 256) {
        int o = idx >> 7, k = idx & 127;
        w16[o * 136 + k] = (_Float16)W[idx];
    }
    __syncthreads();

    const h8* Xv = (const h8*)X;            // 16 h8-chunks per row
    const h8* Wv = (const h8*)w16;          // 17 h8-chunks per row
    int lane = threadIdx.x & 63;
    int lr = lane & 15;                      // row-in-tile / out-col
    int lk = lane >> 4;                      // k-subgroup (0..3)
    int wid = (blockIdx.x * blockDim.x + threadIdx.x) >> 6;
    int nw = (gridDim.x * blockDim.x) >> 6;
    int ntiles = N >> 4;

    for (int tile = wid; tile < ntiles; tile += nw) {
        int r0 = tile << 4;
        h8 a[4];
        #pragma unroll
        for (int kg = 0; kg < 4; ++kg)
            a[kg] = Xv[(long)(r0 + lr) * 16 + kg * 4 + lk];

        f4 acc[8];
        #pragma unroll
        for (int nt = 0; nt < 8; ++nt) acc[nt] = (f4)(0.f);

        #pragma unroll
        for (int nt = 0; nt < 8; ++nt) {
            int o = nt * 16 + lr;
            #pragma unroll
            for (int kg = 0; kg < 4; ++kg) {
                h8 b = Wv[o * 17 + kg * 4 + lk];
                acc[nt] = __builtin_amdgcn_mfma_f32_16x16x32_f16(a[kg], b, acc[nt], 0, 0, 0);
            }
        }

        int rbase = r0 + (lane >> 4) * 4;
        float dv0 = dinv[rbase + 0];
        float dv1 = dinv[rbase + 1];
        float dv2 = dinv[rbase + 2];
        float dv3 = dinv[rbase + 3];
        #pragma unroll
        for (int nt = 0; nt < 8; ++nt) {
            _Float16* dst = Ys + ((long)nt * N) * 16 + lr;
            dst[(long)(rbase + 0) * 16] = (_Float16)(acc[nt][0] * dv0);
            dst[(long)(rbase + 1) * 16] = (_Float16)(acc[nt][1] * dv1);
            dst[(long)(rbase + 2) * 16] = (_Float16)(acc[nt][2] * dv2);
            dst[(long)(rbase + 3) * 16] = (_Float16)(acc[nt][3] * dv3);
        }
    }
}

// ---------------- sliced aggregation: 4-lane groups, uint2/lane, int addressing ---
// block = 64 nodes x slice (blockIdx&7, XCD-pinned; 3.2MB table -> L2-resident).
// wave = 16 groups x 4 lanes; group owns ONE node; lane holds uint2 (8B) of the
// node's 32B slice row -> one gather instr covers 16 edges x 32B. In-lane
// accumulate (zero shuffles). Maskless quad main loop + tiny scalar tail.
// All indices 32-bit -> saddr-form loads, no 64-bit VALU chains.
__global__ __launch_bounds__(256) void k_agg(const uint2* __restrict__ TTs,
    const int* __restrict__ rp, const int* __restrict__ csr,
    const float* __restrict__ dinv, const float* __restrict__ bias,
    uint2* __restrict__ OUT, int N)
{
    int s = blockIdx.x & 7;
    int g = blockIdx.x >> 3;
    int node = g * 64 + (threadIdx.x >> 2);
    if (node >= N) return;
    int ln = threadIdx.x & 3;                    // uint2 slot in 32B slice row
    const uint2* __restrict__ base = TTs + s * (N * 4);   // slice: N rows x 4 uint2

    int e0 = rp[node], e1 = rp[node + 1];
    float a0 = 0.f, a1 = 0.f, a2 = 0.f, a3 = 0.f;
    int e = e0;
    for (; e + 4 <= e1; e += 4) {
        int s0 = csr[e + 0], s1 = csr[e + 1], s2 = csr[e + 2], s3 = csr[e + 3];
        uint2 v0 = base[s0 * 4 + ln];
        uint2 v1 = base[s1 * 4 + ln];
        uint2 v2 = base[s2 * 4 + ln];
        uint2 v3 = base[s3 * 4 + ln];
        float2 p0 = __half22float2(*(const __half2*)&v0.x);
        float2 q0 = __half22float2(*(const __half2*)&v0.y);
        float2 p1 = __half22float2(*(const __half2*)&v1.x);
        float2 q1 = __half22float2(*(const __half2*)&v1.y);
        float2 p2 = __half22float2(*(const __half2*)&v2.x);
        float2 q2 = __half22float2(*(const __half2*)&v2.y);
        float2 p3 = __half22float2(*(const __half2*)&v3.x);
        float2 q3 = __half22float2(*(const __half2*)&v3.y);
        a0 += (p0.x + p1.x) + (p2.x + p3.x);
        a1 += (p0.y + p1.y) + (p2.y + p3.y);
        a2 += (q0.x + q1.x) + (q2.x + q3.x);
        a3 += (q0.y + q1.y) + (q2.y + q3.y);
    }
    for (; e < e1; ++e) {
        int sc = csr[e];
        uint2 v = base[sc * 4 + ln];
        float2 p = __half22float2(*(const __half2*)&v.x);
        float2 q = __half22float2(*(const __half2*)&v.y);
        a0 += p.x; a1 += p.y; a2 += q.x; a3 += q.y;
    }
    uint2 sv = base[node * 4 + ln];              // self-loop term
    float2 sp = __half22float2(*(const __half2*)&sv.x);
    float2 sq = __half22float2(*(const __half2*)&sv.y);
    float dv = dinv[node];
    int fb = s * 16 + ln * 4;
    float o0 = fmaxf(fmaf(a0 + sp.x, dv, bias[fb + 0]), 0.f);
    float o1 = fmaxf(fmaf(a1 + sp.y, dv, bias[fb + 1]), 0.f);
    float o2 = fmaxf(fmaf(a2 + sq.x, dv, bias[fb + 2]), 0.f);
    float o3 = fmaxf(fmaf(a3 + sq.y, dv, bias[fb + 3]), 0.f);
    __half2 h0 = __floats2half2_rn(o0, o1);
    __half2 h1 = __floats2half2_rn(o2, o3);
    uint2 u;
    u.x = *(unsigned int*)&h0;
    u.y = *(unsigned int*)&h1;
    // node row = 128 f16 = 32 uint2
    OUT[node * 32 + s * 4 + ln] = u;
}

// ---------------- fused head: relu(H@Wc1^T + bc1) @ Wc2^T + bc2  (H f16) ---------
__global__ __launch_bounds__(256) void k_head(const __half* __restrict__ H,
    const float* __restrict__ Wc1, const float* __restrict__ bc1,
    const float* __restrict__ Wc2, const float* __restrict__ bc2,
    float* __restrict__ OUT, int N)
{
    __shared__ float w1[16][132];
    __shared__ float hs[16][132];
    __shared__ float h16[16][17];
    for (int idx = threadIdx.x; idx < 16 * NFEAT; idx += 256) {
        int o = idx >> 7, k = idx & 127;
        w1[o][k] = Wc1[idx];
    }
    const unsigned int* Hu = (const unsigned int*)H;
    int ntiles = (N + 15) >> 4;
    for (int tile = blockIdx.x; tile < ntiles; tile += gridDim.x) {
        int row0 = tile << 4;
        __syncthreads();   // also covers w1 init on first iter
        #pragma unroll
        for (int it = 0; it < 4; ++it) {
            int idx = it * 256 + threadIdx.x;   // 0..1023
            int r = idx >> 6, p = idx & 63;
            int row = row0 + r;
            unsigned int v = (row < N) ? Hu[(long)row * 64 + p] : 0u;
            float2 f = __half22float2(*(const __half2*)&v);
            hs[r][p * 2] = f.x;
            hs[r][p * 2 + 1] = f.y;
        }
        __syncthreads();
        int r = threadIdx.x >> 4, o = threadIdx.x & 15;
        float acc = 0.f;
        #pragma unroll 8
        for (int k = 0; k < NFEAT; ++k) acc = fmaf(hs[r][k], w1[o][k], acc);
        h16[r][o] = fmaxf(acc + bc1[o], 0.f);
        __syncthreads();
        if (threadIdx.x < 32) {
            int rr = threadIdx.x >> 1, j = threadIdx.x & 1;
            float a = bc2[j];
            #pragma unroll
            for (int o2 = 0; o2 < 16; ++o2) a = fmaf(h16[rr][o2], Wc2[j * 16 + o2], a);
            int row = row0 + rr;
            if (row < N) OUT[(long)row * 2 + j] = a;
        }
        __syncthreads();
    }
}

extern "C" void kernel_launch(void* const* d_in, const int* in_sizes, int n_in,
                              void* d_out, int out_size, void* d_ws, size_t ws_size,
                              hipStream_t stream) {
    const float* x     = (const float*)d_in[0];
    const int*   ei    = (const int*)d_in[1];
    const float* gamma = (const float*)d_in[2];
    const float* beta  = (const float*)d_in[3];
    const float* W1    = (const float*)d_in[4];
    const float* b1    = (const float*)d_in[5];
    const float* W2    = (const float*)d_in[6];
    const float* b2    = (const float*)d_in[7];
    const float* Wc1   = (const float*)d_in[8];
    const float* bc1   = (const float*)d_in[9];
    const float* Wc2   = (const float*)d_in[10];
    const float* bc2   = (const float*)d_in[11];

    int N = in_sizes[0] / NFEAT;
    int E = in_sizes[1] / 2;
    const int* srcI = ei;
    const int* dstI = ei + E;
    int NB = (N + BSZ - 1) >> BSH;   // 196 for N=100k (<=256 required by k_bscan)

    char* ws = (char*)d_ws;
    size_t off = 0;
    auto alloc = [&](size_t bytes) {
        void* p = ws + off;
        off += bytes;
        off = (off + 511) & ~(size_t)511;
        return p;
    };
    __half* bufA  = (__half*)alloc((size_t)N * NFEAT * 2);   // h buffer (row-major)
    __half* bufB  = (__half*)alloc((size_t)N * NFEAT * 2);   // tt buffer (sliced)
    float* sum    = (float*)alloc(NFEAT * 4);
    float* sumsq  = (float*)alloc(NFEAT * 4);
    int*   deg    = (int*)alloc((size_t)N * 4);
    int*   rp     = (int*)alloc((size_t)(N + 1) * 4);
    float* dinv   = (float*)alloc((size_t)N * 4);
    int*   csr    = (int*)alloc((size_t)E * 4);
    int*   packed = (int*)alloc((size_t)E * 4);
    int*   bcnt   = (int*)alloc((size_t)(NB + 1) * 4);
    int*   boff   = (int*)alloc((size_t)(NB + 1) * 4);
    int*   bnxt   = (int*)alloc((size_t)(NB + 1) * 4);
    int*   part   = (int*)alloc(256 * 4);
    (void)ws_size;

    hipMemsetAsync(sum, 0, NFEAT * 4, stream);
    hipMemsetAsync(sumsq, 0, NFEAT * 4, stream);
    hipMemsetAsync(bcnt, 0, (size_t)(NB + 1) * 4, stream);

    long total = (long)N * NFEAT;
    int nb = (N + 1023) >> 10;          // scan blocks
    int nchunk = (E + 8191) >> 13;      // bucket partition blocks (8192 edges each)
    int naggb = ((N + 63) / 64) * 8;    // agg: node-groups (64 nodes/block) x 8 slices

    k_stats<<<1024, 256, 0, stream>>>(x, sum, sumsq, total);
    k_bn<<<2048, 256, 0, stream>>>(x, sum, sumsq, gamma, beta, bufA, total >> 2, 1.0f / (float)N);

    // graph build (bucketed counting sort, L2-window scatter)
    k_bhist<<<NB, 256, 0, stream>>>(dstI, bcnt, E, NB);
    k_bscan<<<1, 256, 0, stream>>>(bcnt, boff, bnxt, NB);
    k_bucket<<<nchunk, 256, 0, stream>>>(srcI, dstI, bnxt, packed, E, NB);
    k_bdeg<<<NB, 256, 0, stream>>>(packed, boff, deg, N);
    k_scan_a<<<nb, 256, 0, stream>>>(deg, part, N);
    k_scan_b<<<1, 256, 0, stream>>>(part, nb);
    k_scan_c<<<nb, 256, 0, stream>>>(deg, part, rp, dinv, N, E);
    k_place<<<NB, 256, 0, stream>>>(packed, boff, rp, csr, N);

    // layer 1
    k_gemm_mfma<<<512, 256, 0, stream>>>((const _Float16*)bufA, W1, dinv, (_Float16*)bufB, N);
    k_agg<<<naggb, 256, 0, stream>>>((const uint2*)bufB, rp, csr, dinv, b1, (uint2*)bufA, N);
    // layer 2
    k_gemm_mfma<<<512, 256, 0, stream>>>((const _Float16*)bufA, W2, dinv, (_Float16*)bufB, N);
    k_agg<<<naggb, 256, 0, stream>>>((const uint2*)bufB, rp, csr, dinv, b2, (uint2*)bufA, N);
    // head
    k_head<<<2048, 256, 0, stream>>>(bufA, Wc1, bc1, Wc2, bc2, (float*)d_out, N);
}

// Round 10
// 339.777 us; speedup vs baseline: 1.6744x; 1.0803x over previous
//
#include <hip/hip_runtime.h>
#include <hip/hip_fp16.h>

#define NFEAT 128
#define EPSV 1e-5f
#define BSH 9
#define BSZ 512   // nodes per dst-bucket

typedef _Float16 h8 __attribute__((ext_vector_type(8)));   // 8 halfs = 16B
typedef float f4 __attribute__((ext_vector_type(4)));

// ---------------- column stats (mean/var over N rows, 128 cols) ----------------
__global__ __launch_bounds__(256) void k_stats(const float* __restrict__ X,
    float* __restrict__ sum, float* __restrict__ sumsq, long total)
{
    float s = 0.f, q = 0.f;
    long stride = (long)gridDim.x * blockDim.x;
    for (long i = (long)blockIdx.x * blockDim.x + threadIdx.x; i < total; i += stride) {
        float v = X[i];
        s += v;
        q = fmaf(v, v, q);
    }
    __shared__ float ls[256], lq[256];
    ls[threadIdx.x] = s; lq[threadIdx.x] = q;
    __syncthreads();
    if (threadIdx.x < 128) {
        int c = threadIdx.x;            // stride is a multiple of 128 -> col == tid&127
        s = ls[c] + ls[c + 128];
        q = lq[c] + lq[c + 128];
        unsafeAtomicAdd(&sum[c], s);
        unsafeAtomicAdd(&sumsq[c], q);
    }
}

// ---------------- BN apply: xn = (x-mu)*rstd*gamma + beta  (write f16) ----------
__global__ __launch_bounds__(256) void k_bn(const float* __restrict__ X,
    const float* __restrict__ sum, const float* __restrict__ sumsq,
    const float* __restrict__ gamma, const float* __restrict__ beta,
    __half* __restrict__ XN, long total4, float invN)
{
    __shared__ float sc[NFEAT], sh[NFEAT];
    if (threadIdx.x < NFEAT) {
        int c = threadIdx.x;
        float mu = sum[c] * invN;
        float var = fmaf(-mu, mu, sumsq[c] * invN);
        float r = rsqrtf(var + EPSV);
        float g = r * gamma[c];
        sc[c] = g;
        sh[c] = fmaf(-mu, g, beta[c]);
    }
    __syncthreads();
    const float4* X4 = (const float4*)X;
    uint2* XN4 = (uint2*)XN;
    long stride = (long)gridDim.x * blockDim.x;
    for (long i = (long)blockIdx.x * blockDim.x + threadIdx.x; i < total4; i += stride) {
        int c0 = (int)((i << 2) & (NFEAT - 1));
        float4 v = X4[i];
        float4 o;
        o.x = fmaf(v.x, sc[c0 + 0], sh[c0 + 0]);
        o.y = fmaf(v.y, sc[c0 + 1], sh[c0 + 1]);
        o.z = fmaf(v.z, sc[c0 + 2], sh[c0 + 2]);
        o.w = fmaf(v.w, sc[c0 + 3], sh[c0 + 3]);
        __half2 h0 = __floats2half2_rn(o.x, o.y);
        __half2 h1 = __floats2half2_rn(o.z, o.w);
        uint2 u;
        u.x = *(unsigned int*)&h0;
        u.y = *(unsigned int*)&h1;
        XN4[i] = u;
    }
}

// ---------------- bucket histogram over dst>>BSH ----------------
__global__ __launch_bounds__(256) void k_bhist(const int* __restrict__ dst,
    int* __restrict__ bcnt, int E, int NB)
{
    __shared__ int hist[1024];
    for (int i = threadIdx.x; i < NB; i += 256) hist[i] = 0;
    __syncthreads();
    int stride = gridDim.x * 256;
    for (int e = blockIdx.x * 256 + threadIdx.x; e < E; e += stride)
        atomicAdd(&hist[dst[e] >> BSH], 1);
    __syncthreads();
    for (int i = threadIdx.x; i < NB; i += 256)
        if (hist[i]) atomicAdd(&bcnt[i], hist[i]);
}

// ---------------- scan bucket counts (NB <= 256) -> boff[NB+1], bnxt ----------------
__global__ __launch_bounds__(256) void k_bscan(const int* __restrict__ bcnt,
    int* __restrict__ boff, int* __restrict__ bnxt, int NB)
{
    __shared__ int ps[256];
    int t = threadIdx.x;
    int v = (t < NB) ? bcnt[t] : 0;
    ps[t] = v;
    __syncthreads();
    #pragma unroll
    for (int off = 1; off < 256; off <<= 1) {
        int u = ps[t];
        if (t >= off) u += ps[t - off];
        __syncthreads();
        ps[t] = u;
        __syncthreads();
    }
    if (t < NB) {
        int ex = ps[t] - v;
        boff[t] = ex;
        bnxt[t] = ex;
    }
    if (t == NB - 1) boff[NB] = ps[t];
}

// ---------------- partition edges into buckets, packed (src<<BSH | dst&511) ----------
__global__ __launch_bounds__(256) void k_bucket(const int* __restrict__ src,
    const int* __restrict__ dst, int* __restrict__ bnxt,
    int* __restrict__ packed, int E, int NB)
{
    __shared__ int hist[1024];
    __shared__ int base[1024];
    int c0 = blockIdx.x * 8192;
    int c1 = min(E, c0 + 8192);
    for (int i = threadIdx.x; i < NB; i += 256) hist[i] = 0;
    __syncthreads();
    for (int e = c0 + threadIdx.x; e < c1; e += 256)
        atomicAdd(&hist[dst[e] >> BSH], 1);
    __syncthreads();
    for (int i = threadIdx.x; i < NB; i += 256) {
        int h = hist[i];
        base[i] = h ? atomicAdd(&bnxt[i], h) : 0;
        hist[i] = 0;
    }
    __syncthreads();
    for (int e = c0 + threadIdx.x; e < c1; e += 256) {
        int d = dst[e];
        int b = d >> BSH;
        int p = base[b] + atomicAdd(&hist[b], 1);
        packed[p] = (src[e] << BSH) | (d & (BSZ - 1));
    }
}

// ---------------- per-bucket degree (LDS counters -> coalesced deg writes) --------
__global__ __launch_bounds__(256) void k_bdeg(const int* __restrict__ packed,
    const int* __restrict__ boff, int* __restrict__ deg, int N)
{
    __shared__ int cnt[BSZ];
    int b = blockIdx.x;
    for (int i = threadIdx.x; i < BSZ; i += 256) cnt[i] = 0;
    __syncthreads();
    int e0 = boff[b], e1 = boff[b + 1];
    for (int e = e0 + threadIdx.x; e < e1; e += 256)
        atomicAdd(&cnt[packed[e] & (BSZ - 1)], 1);
    __syncthreads();
    int nbase = b << BSH;
    for (int i = threadIdx.x; i < BSZ; i += 256)
        if (nbase + i < N) deg[nbase + i] = cnt[i];
}

// ---------------- 3-phase device-wide exclusive scan ----------------
__global__ __launch_bounds__(256) void k_scan_a(const int* __restrict__ deg,
    int* __restrict__ part, int N)
{
    int base = blockIdx.x << 10;
    int t = threadIdx.x;
    int s = 0;
    #pragma unroll
    for (int j = 0; j < 4; ++j) {
        int i = base + t * 4 + j;
        if (i < N) s += deg[i];
    }
    __shared__ int ls[256];
    ls[t] = s;
    __syncthreads();
    #pragma unroll
    for (int off = 128; off > 0; off >>= 1) {
        if (t < off) ls[t] += ls[t + off];
        __syncthreads();
    }
    if (t == 0) part[blockIdx.x] = ls[0];
}

__global__ __launch_bounds__(256) void k_scan_b(int* __restrict__ part, int nb)
{
    __shared__ int ps[256];
    int t = threadIdx.x;
    int v = (t < nb) ? part[t] : 0;
    ps[t] = v;
    __syncthreads();
    #pragma unroll
    for (int off = 1; off < 256; off <<= 1) {
        int u = ps[t];
        if (t >= off) u += ps[t - off];
        __syncthreads();
        ps[t] = u;
        __syncthreads();
    }
    if (t < nb) part[t] = ps[t] - v;   // exclusive
}

__global__ __launch_bounds__(256) void k_scan_c(const int* __restrict__ deg,
    const int* __restrict__ part, int* __restrict__ rp,
    float* __restrict__ dinv, int N, int E)
{
    int base = blockIdx.x << 10;
    int t = threadIdx.x;
    int v[4];
    int ts = 0;
    #pragma unroll
    for (int j = 0; j < 4; ++j) {
        int i = base + t * 4 + j;
        v[j] = (i < N) ? deg[i] : 0;
        ts += v[j];
    }
    __shared__ int ps[256];
    ps[t] = ts;
    __syncthreads();
    #pragma unroll
    for (int off = 1; off < 256; off <<= 1) {
        int u = ps[t];
        if (t >= off) u += ps[t - off];
        __syncthreads();
        ps[t] = u;
        __syncthreads();
    }
    int run = part[blockIdx.x] + ps[t] - ts;   // exclusive offset for this thread
    #pragma unroll
    for (int j = 0; j < 4; ++j) {
        int i = base + t * 4 + j;
        if (i < N) {
            rp[i] = run;
            dinv[i] = rsqrtf((float)(v[j] + 1));
            run += v[j];
        }
    }
    if (blockIdx.x == 0 && t == 0) rp[N] = E;
}

// ---------------- per-bucket CSR placement (writes confined to 33KB window) ------
__global__ __launch_bounds__(256) void k_place(const int* __restrict__ packed,
    const int* __restrict__ boff, const int* __restrict__ rp,
    int* __restrict__ csr, int N)
{
    __shared__ int nxt[BSZ];
    int b = blockIdx.x;
    int nbase = b << BSH;
    for (int i = threadIdx.x; i < BSZ; i += 256)
        nxt[i] = (nbase + i < N) ? rp[nbase + i] : 0;
    __syncthreads();
    int e0 = boff[b], e1 = boff[b + 1];
    for (int e = e0 + threadIdx.x; e < e1; e += 256) {
        int v = packed[e];
        int p = atomicAdd(&nxt[v & (BSZ - 1)], 1);
        csr[p] = v >> BSH;
    }
}

// ---------------- MFMA GEMM: Y[n][o] = dinv[n]*(X[n]@W^T)[o], ROW-MAJOR out ------
// One wave per 16-row tile (16 | N -> no tail). W staged once/block to LDS f16
// (stride 136 halfs). D-frag (col=lane&15, row=(lane>>4)*4+reg) is staged to a
// wave-private LDS slab, then read back as h8 -> fully coalesced 1KB row-major
// global stores. No __syncthreads needed for the slab (wave-local, lgkmcnt).
__global__ __launch_bounds__(256) void k_gemm_mfma(const _Float16* __restrict__ X,
    const float* __restrict__ W, const float* __restrict__ dinv,
    _Float16* __restrict__ Y, int N)
{
    __shared__ _Float16 w16[NFEAT * 136];    // [o][k], row stride 136 halfs
    __shared__ _Float16 ost[4 * 16 * 136];   // 4 waves x 16 rows x 136 halfs
    for (int idx = threadIdx.x; idx < NFEAT * NFEAT; idx += 256) {
        int o = idx >> 7, k = idx & 127;
        w16[o * 136 + k] = (_Float16)W[idx];
    }
    __syncthreads();

    const h8* Xv = (const h8*)X;            // 16 h8-chunks per row
    const h8* Wv = (const h8*)w16;          // 17 h8-chunks per row
    h8* Yv = (h8*)Y;                         // 16 h8-chunks per row
    int lane = threadIdx.x & 63;
    int lr = lane & 15;                      // A row-in-tile / D out-col
    int lk = lane >> 4;                      // k-subgroup (0..3) / D row-group
    _Float16* slab = ost + (threadIdx.x >> 6) * (16 * 136);
    h8* slabv = (h8*)slab;
    int wid = (blockIdx.x * blockDim.x + threadIdx.x) >> 6;
    int nw = (gridDim.x * blockDim.x) >> 6;
    int ntiles = N >> 4;

    for (int tile = wid; tile < ntiles; tile += nw) {
        int r0 = tile << 4;
        h8 a[4];
        #pragma unroll
        for (int kg = 0; kg < 4; ++kg)
            a[kg] = Xv[(long)(r0 + lr) * 16 + kg * 4 + lk];

        f4 acc[8];
        #pragma unroll
        for (int nt = 0; nt < 8; ++nt) acc[nt] = (f4)(0.f);

        #pragma unroll
        for (int nt = 0; nt < 8; ++nt) {
            int o = nt * 16 + lr;
            #pragma unroll
            for (int kg = 0; kg < 4; ++kg) {
                h8 b = Wv[o * 17 + kg * 4 + lk];
                acc[nt] = __builtin_amdgcn_mfma_f32_16x16x32_f16(a[kg], b, acc[nt], 0, 0, 0);
            }
        }

        int rbase = lk * 4;                  // row-group within tile
        float dv0 = dinv[r0 + rbase + 0];
        float dv1 = dinv[r0 + rbase + 1];
        float dv2 = dinv[r0 + rbase + 2];
        float dv3 = dinv[r0 + rbase + 3];
        #pragma unroll
        for (int nt = 0; nt < 8; ++nt) {
            int c = nt * 16 + lr;
            slab[(rbase + 0) * 136 + c] = (_Float16)(acc[nt][0] * dv0);
            slab[(rbase + 1) * 136 + c] = (_Float16)(acc[nt][1] * dv1);
            slab[(rbase + 2) * 136 + c] = (_Float16)(acc[nt][2] * dv2);
            slab[(rbase + 3) * 136 + c] = (_Float16)(acc[nt][3] * dv3);
        }
        // coalesced writeout: 4 iters x (4 rows x 16 chunks x 16B = 1KB)
        #pragma unroll
        for (int j = 0; j < 4; ++j) {
            int row = j * 4 + lk;
            Yv[(long)(r0 + row) * 16 + lr] = slabv[row * 17 + lr];
        }
    }
}

// ---------------- aggregation (round-4 best): one wave per dst node --------------
// lane = half2 col pair -> 64 lanes x 4B = full 256B row per edge (line-efficient
// single gather request per edge). In-lane f32 accumulate, zero shuffles.
__global__ __launch_bounds__(256) void k_agg(const unsigned int* __restrict__ TT,
    const int* __restrict__ rp, const int* __restrict__ csr,
    const float* __restrict__ dinv, const float* __restrict__ bias,
    unsigned int* __restrict__ OUT, int N)
{
    int wid = (blockIdx.x * 256 + threadIdx.x) >> 6;
    if (wid >= N) return;
    int lane = threadIdx.x & 63;
    unsigned int sv = TT[wid * 64 + lane];
    float2 acc = __half22float2(*(const __half2*)&sv);   // self-loop term
    int e = rp[wid], e1 = rp[wid + 1];
    for (; e + 8 <= e1; e += 8) {
        int s0 = csr[e + 0], s1 = csr[e + 1], s2 = csr[e + 2], s3 = csr[e + 3];
        int s4 = csr[e + 4], s5 = csr[e + 5], s6 = csr[e + 6], s7 = csr[e + 7];
        unsigned int v0 = TT[s0 * 64 + lane];
        unsigned int v1 = TT[s1 * 64 + lane];
        unsigned int v2 = TT[s2 * 64 + lane];
        unsigned int v3 = TT[s3 * 64 + lane];
        unsigned int v4 = TT[s4 * 64 + lane];
        unsigned int v5 = TT[s5 * 64 + lane];
        unsigned int v6 = TT[s6 * 64 + lane];
        unsigned int v7 = TT[s7 * 64 + lane];
        float2 f0 = __half22float2(*(const __half2*)&v0);
        float2 f1 = __half22float2(*(const __half2*)&v1);
        float2 f2 = __half22float2(*(const __half2*)&v2);
        float2 f3 = __half22float2(*(const __half2*)&v3);
        float2 f4_ = __half22float2(*(const __half2*)&v4);
        float2 f5 = __half22float2(*(const __half2*)&v5);
        float2 f6 = __half22float2(*(const __half2*)&v6);
        float2 f7 = __half22float2(*(const __half2*)&v7);
        acc.x += ((f0.x + f1.x) + (f2.x + f3.x)) + ((f4_.x + f5.x) + (f6.x + f7.x));
        acc.y += ((f0.y + f1.y) + (f2.y + f3.y)) + ((f4_.y + f5.y) + (f6.y + f7.y));
    }
    for (; e < e1; ++e) {
        int s = csr[e];
        unsigned int v = TT[s * 64 + lane];
        float2 f = __half22float2(*(const __half2*)&v);
        acc.x += f.x; acc.y += f.y;
    }
    float dv = dinv[wid];
    float ox = fmaxf(fmaf(acc.x, dv, bias[lane * 2 + 0]), 0.f);
    float oy = fmaxf(fmaf(acc.y, dv, bias[lane * 2 + 1]), 0.f);
    __half2 o2 = __floats2half2_rn(ox, oy);
    OUT[wid * 64 + lane] = *(unsigned int*)&o2;
}

// ---------------- fused head: relu(H@Wc1^T + bc1) @ Wc2^T + bc2  (H f16) ---------
__global__ __launch_bounds__(256) void k_head(const __half* __restrict__ H,
    const float* __restrict__ Wc1, const float* __restrict__ bc1,
    const float* __restrict__ Wc2, const float* __restrict__ bc2,
    float* __restrict__ OUT, int N)
{
    __shared__ float w1[16][132];
    __shared__ float hs[16][132];
    __shared__ float h16[16][17];
    for (int idx = threadIdx.x; idx < 16 * NFEAT; idx += 256) {
        int o = idx >> 7, k = idx & 127;
        w1[o][k] = Wc1[idx];
    }
    const unsigned int* Hu = (const unsigned int*)H;
    int ntiles = (N + 15) >> 4;
    for (int tile = blockIdx.x; tile < ntiles; tile += gridDim.x) {
        int row0 = tile << 4;
        __syncthreads();   // also covers w1 init on first iter
        #pragma unroll
        for (int it = 0; it < 4; ++it) {
            int idx = it * 256 + threadIdx.x;   // 0..1023
            int r = idx >> 6, p = idx & 63;
            int row = row0 + r;
            unsigned int v = (row < N) ? Hu[(long)row * 64 + p] : 0u;
            float2 f = __half22float2(*(const __half2*)&v);
            hs[r][p * 2] = f.x;
            hs[r][p * 2 + 1] = f.y;
        }
        __syncthreads();
        int r = threadIdx.x >> 4, o = threadIdx.x & 15;
        float acc = 0.f;
        #pragma unroll 8
        for (int k = 0; k < NFEAT; ++k) acc = fmaf(hs[r][k], w1[o][k], acc);
        h16[r][o] = fmaxf(acc + bc1[o], 0.f);
        __syncthreads();
        if (threadIdx.x < 32) {
            int rr = threadIdx.x >> 1, j = threadIdx.x & 1;
            float a = bc2[j];
            #pragma unroll
            for (int o2 = 0; o2 < 16; ++o2) a = fmaf(h16[rr][o2], Wc2[j * 16 + o2], a);
            int row = row0 + rr;
            if (row < N) OUT[(long)row * 2 + j] = a;
        }
        __syncthreads();
    }
}

extern "C" void kernel_launch(void* const* d_in, const int* in_sizes, int n_in,
                              void* d_out, int out_size, void* d_ws, size_t ws_size,
                              hipStream_t stream) {
    const float* x     = (const float*)d_in[0];
    const int*   ei    = (const int*)d_in[1];
    const float* gamma = (const float*)d_in[2];
    const float* beta  = (const float*)d_in[3];
    const float* W1    = (const float*)d_in[4];
    const float* b1    = (const float*)d_in[5];
    const float* W2    = (const float*)d_in[6];
    const float* b2    = (const float*)d_in[7];
    const float* Wc1   = (const float*)d_in[8];
    const float* bc1   = (const float*)d_in[9];
    const float* Wc2   = (const float*)d_in[10];
    const float* bc2   = (const float*)d_in[11];

    int N = in_sizes[0] / NFEAT;
    int E = in_sizes[1] / 2;
    const int* srcI = ei;
    const int* dstI = ei + E;
    int NB = (N + BSZ - 1) >> BSH;   // 196 for N=100k (<=256 required by k_bscan)

    char* ws = (char*)d_ws;
    size_t off = 0;
    auto alloc = [&](size_t bytes) {
        void* p = ws + off;
        off += bytes;
        off = (off + 511) & ~(size_t)511;
        return p;
    };
    __half* bufA  = (__half*)alloc((size_t)N * NFEAT * 2);   // h buffer (row-major)
    __half* bufB  = (__half*)alloc((size_t)N * NFEAT * 2);   // tt buffer (row-major)
    float* sum    = (float*)alloc(NFEAT * 4);
    float* sumsq  = (float*)alloc(NFEAT * 4);
    int*   deg    = (int*)alloc((size_t)N * 4);
    int*   rp     = (int*)alloc((size_t)(N + 1) * 4);
    float* dinv   = (float*)alloc((size_t)N * 4);
    int*   csr    = (int*)alloc((size_t)E * 4);
    int*   packed = (int*)alloc((size_t)E * 4);
    int*   bcnt   = (int*)alloc((size_t)(NB + 1) * 4);
    int*   boff   = (int*)alloc((size_t)(NB + 1) * 4);
    int*   bnxt   = (int*)alloc((size_t)(NB + 1) * 4);
    int*   part   = (int*)alloc(256 * 4);
    (void)ws_size;

    hipMemsetAsync(sum, 0, NFEAT * 4, stream);
    hipMemsetAsync(sumsq, 0, NFEAT * 4, stream);
    hipMemsetAsync(bcnt, 0, (size_t)(NB + 1) * 4, stream);

    long total = (long)N * NFEAT;
    int nb = (N + 1023) >> 10;          // scan blocks
    int nchunk = (E + 8191) >> 13;      // bucket partition blocks (8192 edges each)
    int naggb = (N + 3) / 4;            // agg: one wave per node, 4 waves/block

    k_stats<<<1024, 256, 0, stream>>>(x, sum, sumsq, total);
    k_bn<<<2048, 256, 0, stream>>>(x, sum, sumsq, gamma, beta, bufA, total >> 2, 1.0f / (float)N);

    // graph build (bucketed counting sort, L2-window scatter)
    k_bhist<<<NB, 256, 0, stream>>>(dstI, bcnt, E, NB);
    k_bscan<<<1, 256, 0, stream>>>(bcnt, boff, bnxt, NB);
    k_bucket<<<nchunk, 256, 0, stream>>>(srcI, dstI, bnxt, packed, E, NB);
    k_bdeg<<<NB, 256, 0, stream>>>(packed, boff, deg, N);
    k_scan_a<<<nb, 256, 0, stream>>>(deg, part, N);
    k_scan_b<<<1, 256, 0, stream>>>(part, nb);
    k_scan_c<<<nb, 256, 0, stream>>>(deg, part, rp, dinv, N, E);
    k_place<<<NB, 256, 0, stream>>>(packed, boff, rp, csr, N);

    // layer 1
    k_gemm_mfma<<<512, 256, 0, stream>>>((const _Float16*)bufA, W1, dinv, (_Float16*)bufB, N);
    k_agg<<<naggb, 256, 0, stream>>>((const unsigned int*)bufB, rp, csr, dinv, b1, (unsigned int*)bufA, N);
    // layer 2
    k_gemm_mfma<<<512, 256, 0, stream>>>((const _Float16*)bufA, W2, dinv, (_Float16*)bufB, N);
    k_agg<<<naggb, 256, 0, stream>>>((const unsigned int*)bufB, rp, csr, dinv, b2, (unsigned int*)bufA, N);
    // head
    k_head<<<2048, 256, 0, stream>>>(bufA, Wc1, bc1, Wc2, bc2, (float*)d_out, N);
}